// Round 1
// baseline (1007.222 us; speedup 1.0000x reference)
//
#include <hip/hip_runtime.h>
#include <hip/hip_bf16.h>

// ---------------------------------------------------------------------------
// MambaBlock: delta/dbar via bf16 MFMA GEMM1 (softplus+row-mean epilogue),
// Bt/Ct small projections, chunk-parallel linear scan, out = diag(s)*(x@Wo)+bo
// via bf16 MFMA GEMM2 (row-scale epilogue).
// B=8 T=4096 D=1024 N=16, M=B*T=32768.
// ---------------------------------------------------------------------------

typedef __bf16 bfx4 __attribute__((ext_vector_type(4)));
typedef __bf16 bfx8 __attribute__((ext_vector_type(8)));
typedef float  f32x4 __attribute__((ext_vector_type(4)));

#define M_ROWS 32768
#define DDIM   1024
#define NSTATE 16
#define TLEN   4096
#define BATCH  8
#define CHUNK  64
#define NCHUNK 64   // TLEN / CHUNK

// ---------------- prep: weight transposes + casts --------------------------
__global__ __launch_bounds__(256) void prep_w_kernel(
    const float* __restrict__ Wd, const float* __restrict__ Wo,
    const float* __restrict__ Wb, const float* __restrict__ Wc,
    __bf16* __restrict__ WdT, __bf16* __restrict__ WoT,
    float* __restrict__ WbT, float* __restrict__ WcT)
{
    int idx = blockIdx.x * 256 + threadIdx.x;
    if (idx < 1048576) {
        int n = idx >> 10, k = idx & 1023;
        WdT[idx] = (__bf16)Wd[k * 1024 + n];
    } else if (idx < 2097152) {
        int j = idx - 1048576;
        int n = j >> 10, k = j & 1023;
        WoT[j] = (__bf16)Wo[k * 1024 + n];
    } else if (idx < 2113536) {
        int j = idx - 2097152;
        int n = j >> 10, k = j & 1023;
        WbT[j] = Wb[k * 16 + n];
    } else if (idx < 2129920) {
        int j = idx - 2113536;
        int n = j >> 10, k = j & 1023;
        WcT[j] = Wc[k * 16 + n];
    }
}

__global__ __launch_bounds__(256) void sA_kernel(const float* __restrict__ A,
                                                 float* __restrict__ sA)
{
    __shared__ float red[256];
    int tid = threadIdx.x;
    int n = tid & 15, part = tid >> 4;
    float sum = 0.f;
    for (int k = part * 64; k < part * 64 + 64; ++k) sum += A[k * 16 + n];
    red[tid] = sum;
    __syncthreads();
    if (tid < 16) {
        float tot = 0.f;
        for (int p = 0; p < 16; ++p) tot += red[p * 16 + tid];
        sA[tid] = 1.f / (1.f + expf(-tot * (1.f / 1024.f)));
    }
}

// ------------- prep_x: cast x->bf16, compute Bt, Ct ------------------------
// 16 rows per block of 256 threads. Rows staged in LDS (fp32), bf16 written out.
__global__ __launch_bounds__(256) void prep_x_kernel(
    const float* __restrict__ x, const float* __restrict__ WbT,
    const float* __restrict__ WcT, const float* __restrict__ bb,
    const float* __restrict__ bc, __bf16* __restrict__ xb,
    float* __restrict__ Bt, float* __restrict__ Ct)
{
    __shared__ float xs[16 * 1024];
    const int tid = threadIdx.x;
    const int rb = blockIdx.x * 16;
    const float4* xg = (const float4*)(x + (size_t)rb * 1024);
    float4* xs4 = (float4*)xs;
    bfx4* xb4 = (bfx4*)(xb + (size_t)rb * 1024);
#pragma unroll
    for (int it = 0; it < 16; ++it) {
        int slot = it * 256 + tid;
        float4 v = xg[slot];
        xs4[slot] = v;
        bfx4 o;
        o[0] = (__bf16)v.x; o[1] = (__bf16)v.y;
        o[2] = (__bf16)v.z; o[3] = (__bf16)v.w;
        xb4[slot] = o;
    }
    __syncthreads();
    const int r = tid >> 4, n = tid & 15;
    const float4* xr = (const float4*)(xs + r * 1024);
    const float4* wb = (const float4*)(WbT + n * 1024);
    const float4* wc = (const float4*)(WcT + n * 1024);
    float accB = 0.f, accC = 0.f;
#pragma unroll 4
    for (int k = 0; k < 256; ++k) {
        float4 xv = xr[k], bv = wb[k], cv = wc[k];
        accB += xv.x * bv.x + xv.y * bv.y + xv.z * bv.z + xv.w * bv.w;
        accC += xv.x * cv.x + xv.y * cv.y + xv.z * cv.z + xv.w * cv.w;
    }
    int row = rb + r;
    Bt[row * 16 + n] = accB + bb[n];
    Ct[row * 16 + n] = accC + bc[n];
}

// ------------------------- MFMA GEMM core ----------------------------------
// C(128x128) += A(128xK) * B^T(128xK)^T ; A,B row-major [row][k], K=1024, BK=32.
__device__ __forceinline__ void gload16(const void* g, void* l)
{
    __builtin_amdgcn_global_load_lds((__attribute__((address_space(1))) void*)g,
                                     (__attribute__((address_space(3))) void*)l,
                                     16, 0, 0);
}

__device__ __forceinline__ void gemm_core(const __bf16* __restrict__ Abuf,
                                          const __bf16* __restrict__ Bbuf,
                                          __bf16* As, __bf16* Bs,
                                          int mbase, int nbase,
                                          f32x4 acc[4][4])
{
    const int tid = threadIdx.x;
    const int lane = tid & 63;
    const int w = tid >> 6;
    const int quad = lane >> 4;
    const int l15 = lane & 15;
    const int wm = w >> 1, wn = w & 1;

    int lin0 = (w * 2 + 0) * 64 + lane;
    int lin1 = (w * 2 + 1) * 64 + lane;
    const __bf16* gA0 = Abuf + (size_t)(mbase + (lin0 >> 2)) * DDIM + (lin0 & 3) * 8;
    const __bf16* gA1 = Abuf + (size_t)(mbase + (lin1 >> 2)) * DDIM + (lin1 & 3) * 8;
    const __bf16* gB0 = Bbuf + (size_t)(nbase + (lin0 >> 2)) * DDIM + (lin0 & 3) * 8;
    const __bf16* gB1 = Bbuf + (size_t)(nbase + (lin1 >> 2)) * DDIM + (lin1 & 3) * 8;
    __bf16* lA0 = As + (w * 2 + 0) * 512;
    __bf16* lA1 = As + (w * 2 + 1) * 512;
    __bf16* lB0 = Bs + (w * 2 + 0) * 512;
    __bf16* lB1 = Bs + (w * 2 + 1) * 512;

    const __bf16* fa = As + (wm * 64 + l15) * 32 + quad * 8;
    const __bf16* fb = Bs + (wn * 64 + l15) * 32 + quad * 8;

#pragma unroll 1
    for (int kt = 0; kt < DDIM / 32; ++kt) {
        __syncthreads();   // protect LDS from overwrite while prior frags in use
        gload16(gA0, lA0); gload16(gA1, lA1);
        gload16(gB0, lB0); gload16(gB1, lB1);
        gA0 += 32; gA1 += 32; gB0 += 32; gB1 += 32;
        __syncthreads();   // compiler emits vmcnt(0) drain before s_barrier
        bfx8 af[4], bfr[4];
#pragma unroll
        for (int i = 0; i < 4; ++i) {
            af[i]  = *(const bfx8*)(fa + i * 512);
            bfr[i] = *(const bfx8*)(fb + i * 512);
        }
#pragma unroll
        for (int i = 0; i < 4; ++i)
#pragma unroll
            for (int j = 0; j < 4; ++j)
                acc[i][j] = __builtin_amdgcn_mfma_f32_16x16x32_bf16(
                    af[i], bfr[j], acc[i][j], 0, 0, 0);
    }
}

// GEMM1: z = x@Wd + bd ; dbar[row] += mean_cols softplus(z)
__global__ __launch_bounds__(256) void gemm1_kernel(
    const __bf16* __restrict__ xb, const __bf16* __restrict__ WdT,
    const float* __restrict__ bd, float* __restrict__ dbar)
{
    __shared__ __bf16 As[128 * 32];
    __shared__ __bf16 Bs[128 * 32];
    f32x4 acc[4][4];
    f32x4 z4 = {0.f, 0.f, 0.f, 0.f};
#pragma unroll
    for (int i = 0; i < 4; ++i)
#pragma unroll
        for (int j = 0; j < 4; ++j) acc[i][j] = z4;

    const int mbase = blockIdx.y * 128;
    const int nbase = blockIdx.x * 128;
    gemm_core(xb, WdT, As, Bs, mbase, nbase, acc);

    const int lane = threadIdx.x & 63;
    const int w = threadIdx.x >> 6;
    const int quad = lane >> 4;
    const int l15 = lane & 15;
    const int wm = w >> 1, wn = w & 1;
    const float invD = 1.0f / 1024.0f;
#pragma unroll
    for (int i = 0; i < 4; ++i) {
#pragma unroll
        for (int r = 0; r < 4; ++r) {
            float sp = 0.f;
#pragma unroll
            for (int j = 0; j < 4; ++j) {
                int col = nbase + wn * 64 + j * 16 + l15;
                float z = acc[i][j][r] + bd[col];
                sp += fmaxf(z, 0.f) + log1pf(__expf(-fabsf(z)));
            }
#pragma unroll
            for (int off = 1; off < 16; off <<= 1) sp += __shfl_xor(sp, off, 16);
            if (l15 == 0) {
                int row = mbase + wm * 64 + i * 16 + quad * 4 + r;
                atomicAdd(&dbar[row], sp * invD);
            }
        }
    }
}

// GEMM2: out[row][col] = s[row]*(x@Wo)[row][col] + bo[col]
__global__ __launch_bounds__(256) void gemm2_kernel(
    const __bf16* __restrict__ xb, const __bf16* __restrict__ WoT,
    const float* __restrict__ srow, const float* __restrict__ bo,
    float* __restrict__ out)
{
    __shared__ __bf16 As[128 * 32];
    __shared__ __bf16 Bs[128 * 32];
    f32x4 acc[4][4];
    f32x4 z4 = {0.f, 0.f, 0.f, 0.f};
#pragma unroll
    for (int i = 0; i < 4; ++i)
#pragma unroll
        for (int j = 0; j < 4; ++j) acc[i][j] = z4;

    const int mbase = blockIdx.y * 128;
    const int nbase = blockIdx.x * 128;
    gemm_core(xb, WoT, As, Bs, mbase, nbase, acc);

    const int lane = threadIdx.x & 63;
    const int w = threadIdx.x >> 6;
    const int quad = lane >> 4;
    const int l15 = lane & 15;
    const int wm = w >> 1, wn = w & 1;
#pragma unroll
    for (int i = 0; i < 4; ++i) {
        int row0 = mbase + wm * 64 + i * 16 + quad * 4;
#pragma unroll
        for (int r = 0; r < 4; ++r) {
            float sv = srow[row0 + r];
#pragma unroll
            for (int j = 0; j < 4; ++j) {
                int col = nbase + wn * 64 + j * 16 + l15;
                out[(size_t)(row0 + r) * 1024 + col] = sv * acc[i][j][r] + bo[col];
            }
        }
    }
}

// --------------------- chunk-parallel linear scan --------------------------
// h_t = (1-dbar_t) h_{t-1} + dbar_t * Bt_t * sA ;  s_t = <h_t, Ct_t>
// per (b, chunk): local scan from 0, storing s_local, prefix product p.
__global__ __launch_bounds__(256) void scan_kernel(
    const float* __restrict__ dbar, const float* __restrict__ Bt,
    const float* __restrict__ Ct, const float* __restrict__ sA,
    float* __restrict__ s_local, float* __restrict__ pbuf,
    float* __restrict__ Pc, float* __restrict__ Hend)
{
    int tid = threadIdx.x;
    int gid = blockIdx.x * 16 + (tid >> 4);   // 512 groups
    int n = tid & 15;
    int b = gid >> 6;        // / NCHUNK
    int c = gid & 63;        // % NCHUNK
    float sAn = sA[n];
    float h = 0.f, p = 1.f;
    int row = b * TLEN + c * CHUNK;
#pragma unroll 4
    for (int t = 0; t < CHUNK; ++t, ++row) {
        float d = dbar[row];
        float btv = Bt[row * 16 + n];
        float ctv = Ct[row * 16 + n];
        float a = 1.f - d;
        h = h * a + d * sAn * btv;
        p *= a;
        float prod = h * ctv;
#pragma unroll
        for (int off = 1; off < 16; off <<= 1) prod += __shfl_xor(prod, off, 16);
        if (n == 0) { s_local[row] = prod; pbuf[row] = p; }
    }
    Hend[gid * 16 + n] = h;
    if (n == 0) Pc[gid] = p;
}

__global__ __launch_bounds__(128) void stitch_kernel(
    const float* __restrict__ Pc, const float* __restrict__ Hend,
    float* __restrict__ h0buf)
{
    int tid = threadIdx.x;           // 128 = 8 batches x 16 n
    int b = tid >> 4, n = tid & 15;
    float h0 = 0.f;
#pragma unroll 8
    for (int c = 0; c < NCHUNK; ++c) {
        int g = b * NCHUNK + c;
        h0buf[g * 16 + n] = h0;
        h0 = Pc[g] * h0 + Hend[g * 16 + n];
    }
}

__global__ __launch_bounds__(256) void fixup_kernel(
    const float* __restrict__ s_local, const float* __restrict__ pbuf,
    const float* __restrict__ h0buf, const float* __restrict__ Ct,
    float* __restrict__ sbuf)
{
    int row = blockIdx.x * 256 + threadIdx.x;
    int b = row >> 12, t = row & 4095;
    int g = b * NCHUNK + (t >> 6);
    const float4* h4 = (const float4*)(h0buf + g * 16);
    const float4* c4 = (const float4*)(Ct + (size_t)row * 16);
    float dot = 0.f;
#pragma unroll
    for (int q = 0; q < 4; ++q) {
        float4 hv = h4[q], cv = c4[q];
        dot += hv.x * cv.x + hv.y * cv.y + hv.z * cv.z + hv.w * cv.w;
    }
    sbuf[row] = s_local[row] + pbuf[row] * dot;
}

// ---------------------------------------------------------------------------
extern "C" void kernel_launch(void* const* d_in, const int* in_sizes, int n_in,
                              void* d_out, int out_size, void* d_ws, size_t ws_size,
                              hipStream_t stream)
{
    const float* x  = (const float*)d_in[0];
    const float* Wd = (const float*)d_in[1];
    const float* bd = (const float*)d_in[2];
    const float* Wb = (const float*)d_in[3];
    const float* bb = (const float*)d_in[4];
    const float* Wc = (const float*)d_in[5];
    const float* bc = (const float*)d_in[6];
    const float* Wo = (const float*)d_in[7];
    const float* bo = (const float*)d_in[8];
    const float* A  = (const float*)d_in[9];
    float* out = (float*)d_out;

    char* base = (char*)d_ws;
    size_t off = 0;
    auto alloc = [&](size_t bytes) -> void* {
        void* p = base + off;
        off = (off + bytes + 255) & ~(size_t)255;
        return p;
    };
    __bf16* xb   = (__bf16*)alloc((size_t)M_ROWS * DDIM * 2);  // 67 MB
    __bf16* WdT  = (__bf16*)alloc((size_t)DDIM * DDIM * 2);    // 2 MB
    __bf16* WoT  = (__bf16*)alloc((size_t)DDIM * DDIM * 2);    // 2 MB
    float* WbT   = (float*)alloc(16 * 1024 * 4);
    float* WcT   = (float*)alloc(16 * 1024 * 4);
    float* sAbuf = (float*)alloc(64);
    float* dbar  = (float*)alloc(M_ROWS * 4);
    float* Bt    = (float*)alloc((size_t)M_ROWS * 16 * 4);     // 2 MB
    float* Ct    = (float*)alloc((size_t)M_ROWS * 16 * 4);     // 2 MB
    float* s_loc = (float*)alloc(M_ROWS * 4);
    float* pbuf  = (float*)alloc(M_ROWS * 4);
    float* sbuf  = (float*)alloc(M_ROWS * 4);
    float* Pc    = (float*)alloc(BATCH * NCHUNK * 4);
    float* Hend  = (float*)alloc(BATCH * NCHUNK * 16 * 4);
    float* h0buf = (float*)alloc(BATCH * NCHUNK * 16 * 4);

    prep_w_kernel<<<8320, 256, 0, stream>>>(Wd, Wo, Wb, Wc, WdT, WoT, WbT, WcT);
    sA_kernel<<<1, 256, 0, stream>>>(A, sAbuf);
    prep_x_kernel<<<M_ROWS / 16, 256, 0, stream>>>(x, WbT, WcT, bb, bc, xb, Bt, Ct);
    hipMemsetAsync(dbar, 0, M_ROWS * 4, stream);
    gemm1_kernel<<<dim3(8, 256), 256, 0, stream>>>(xb, WdT, bd, dbar);
    scan_kernel<<<32, 256, 0, stream>>>(dbar, Bt, Ct, sAbuf, s_loc, pbuf, Pc, Hend);
    stitch_kernel<<<1, 128, 0, stream>>>(Pc, Hend, h0buf);
    fixup_kernel<<<M_ROWS / 256, 256, 0, stream>>>(s_loc, pbuf, h0buf, Ct, sbuf);
    gemm2_kernel<<<dim3(8, 256), 256, 0, stream>>>(xb, WoT, sbuf, bo, out);
}

// Round 2
// 602.428 us; speedup vs baseline: 1.6719x; 1.6719x over previous
//
#include <hip/hip_runtime.h>
#include <hip/hip_bf16.h>

// ---------------------------------------------------------------------------
// MambaBlock: delta/dbar via bf16 MFMA GEMM1 (softplus+row-mean epilogue),
// Bt/Ct via skinny MFMA GEMM, chunk-parallel linear scan,
// out = diag(s)*(x@Wo)+bo via bf16 MFMA GEMM2 (row-scale epilogue).
// B=8 T=4096 D=1024 N=16, M=B*T=32768.
// ---------------------------------------------------------------------------

typedef __bf16 bfx4 __attribute__((ext_vector_type(4)));
typedef __bf16 bfx8 __attribute__((ext_vector_type(8)));
typedef float  f32x4 __attribute__((ext_vector_type(4)));

#define M_ROWS 32768
#define DDIM   1024
#define NSTATE 16
#define TLEN   4096
#define BATCH  8
#define CHUNK  64
#define NCHUNK 64   // TLEN / CHUNK

// ---------------- prep: weight transposes + casts --------------------------
// Tiled transpose fp32 -> bf16 for Wd, Wo (1024x1024). 32x32 LDS tiles, +1 pad.
__global__ __launch_bounds__(256) void transpose_w_kernel(
    const float* __restrict__ Wd, const float* __restrict__ Wo,
    __bf16* __restrict__ WdT, __bf16* __restrict__ WoT)
{
    __shared__ float tile[32][33];
    const int bid = blockIdx.x;                 // 0..2047
    const float* src = (bid < 1024) ? Wd : Wo;
    __bf16* dst = (bid < 1024) ? WdT : WoT;
    const int t = bid & 1023;
    const int tr = t >> 5, tc = t & 31;
    const int tx = threadIdx.x & 31, ty = threadIdx.x >> 5;  // ty 0..7
#pragma unroll
    for (int i = 0; i < 4; ++i) {
        int r = ty + i * 8;
        tile[r][tx] = src[(size_t)(tr * 32 + r) * 1024 + tc * 32 + tx];
    }
    __syncthreads();
#pragma unroll
    for (int i = 0; i < 4; ++i) {
        int r = ty + i * 8;
        dst[(size_t)(tc * 32 + r) * 1024 + tr * 32 + tx] = (__bf16)tile[tx][r];
    }
}

// Wbc: [32][1024] bf16 ; rows 0..15 = Wb^T, rows 16..31 = Wc^T
__global__ __launch_bounds__(256) void wbc_kernel(
    const float* __restrict__ Wb, const float* __restrict__ Wc,
    __bf16* __restrict__ Wbc)
{
    int idx = blockIdx.x * 256 + threadIdx.x;   // 0..32767
    int n2 = idx >> 10, k = idx & 1023;
    float v = (n2 < 16) ? Wb[k * 16 + n2] : Wc[k * 16 + (n2 - 16)];
    Wbc[idx] = (__bf16)v;
}

__global__ __launch_bounds__(256) void sA_kernel(const float* __restrict__ A,
                                                 float* __restrict__ sA)
{
    __shared__ float red[256];
    int tid = threadIdx.x;
    int n = tid & 15, part = tid >> 4;
    float sum = 0.f;
    for (int k = part * 64; k < part * 64 + 64; ++k) sum += A[k * 16 + n];
    red[tid] = sum;
    __syncthreads();
    if (tid < 16) {
        float tot = 0.f;
        for (int p = 0; p < 16; ++p) tot += red[p * 16 + tid];
        sA[tid] = 1.f / (1.f + expf(-tot * (1.f / 1024.f)));
    }
}

// ------------------ cast x -> bf16 (pure streaming) ------------------------
__global__ __launch_bounds__(256) void cast_kernel(const float* __restrict__ x,
                                                   __bf16* __restrict__ xb)
{
    size_t i = ((size_t)blockIdx.x * 256 + threadIdx.x) * 8;
    const float4* xg = (const float4*)(x + i);
    float4 v0 = xg[0], v1 = xg[1];
    bfx8 o;
    o[0] = (__bf16)v0.x; o[1] = (__bf16)v0.y; o[2] = (__bf16)v0.z; o[3] = (__bf16)v0.w;
    o[4] = (__bf16)v1.x; o[5] = (__bf16)v1.y; o[6] = (__bf16)v1.z; o[7] = (__bf16)v1.w;
    *(bfx8*)(xb + i) = o;
}

// ---------------- Bt/Ct: skinny MFMA GEMM, no LDS --------------------------
// One wave per 16 rows. Per K-step: A frag (16x32), two B frags (Bt/Ct cols).
__global__ __launch_bounds__(256) void btct_kernel(
    const __bf16* __restrict__ xb, const __bf16* __restrict__ Wbc,
    const float* __restrict__ bb, const float* __restrict__ bc,
    float* __restrict__ Bt, float* __restrict__ Ct)
{
    const int wid = blockIdx.x * 4 + (threadIdx.x >> 6);  // 0..2047
    const int lane = threadIdx.x & 63;
    const int quad = lane >> 4, l15 = lane & 15;
    const int mbase = wid * 16;
    const __bf16* ga = xb + (size_t)(mbase + l15) * 1024 + quad * 8;
    const __bf16* gb = Wbc + (size_t)l15 * 1024 + quad * 8;
    const __bf16* gc = Wbc + (size_t)(16 + l15) * 1024 + quad * 8;
    f32x4 accB = {0.f, 0.f, 0.f, 0.f};
    f32x4 accC = {0.f, 0.f, 0.f, 0.f};
#pragma unroll 4
    for (int k = 0; k < 1024; k += 32) {
        bfx8 a = *(const bfx8*)ga;  ga += 32;
        bfx8 b = *(const bfx8*)gb;  gb += 32;
        bfx8 c = *(const bfx8*)gc;  gc += 32;
        accB = __builtin_amdgcn_mfma_f32_16x16x32_bf16(a, b, accB, 0, 0, 0);
        accC = __builtin_amdgcn_mfma_f32_16x16x32_bf16(a, c, accC, 0, 0, 0);
    }
    // C/D layout: col = lane&15, row = quad*4 + r
#pragma unroll
    for (int r = 0; r < 4; ++r) {
        int row = mbase + quad * 4 + r;
        Bt[row * 16 + l15] = accB[r] + bb[l15];
        Ct[row * 16 + l15] = accC[r] + bc[l15];
    }
}

// ------------------------- MFMA GEMM core ----------------------------------
// C(128x128) += A(128xK) * B^T(128xK)^T ; A,B row-major [row][k], K=1024, BK=32.
__device__ __forceinline__ void gload16(const void* g, void* l)
{
    __builtin_amdgcn_global_load_lds((__attribute__((address_space(1))) void*)g,
                                     (__attribute__((address_space(3))) void*)l,
                                     16, 0, 0);
}

__device__ __forceinline__ void gemm_core(const __bf16* __restrict__ Abuf,
                                          const __bf16* __restrict__ Bbuf,
                                          __bf16* As, __bf16* Bs,
                                          int mbase, int nbase,
                                          f32x4 acc[4][4])
{
    const int tid = threadIdx.x;
    const int lane = tid & 63;
    const int w = tid >> 6;
    const int quad = lane >> 4;
    const int l15 = lane & 15;
    const int wm = w >> 1, wn = w & 1;

    int lin0 = (w * 2 + 0) * 64 + lane;
    int lin1 = (w * 2 + 1) * 64 + lane;
    const __bf16* gA0 = Abuf + (size_t)(mbase + (lin0 >> 2)) * DDIM + (lin0 & 3) * 8;
    const __bf16* gA1 = Abuf + (size_t)(mbase + (lin1 >> 2)) * DDIM + (lin1 & 3) * 8;
    const __bf16* gB0 = Bbuf + (size_t)(nbase + (lin0 >> 2)) * DDIM + (lin0 & 3) * 8;
    const __bf16* gB1 = Bbuf + (size_t)(nbase + (lin1 >> 2)) * DDIM + (lin1 & 3) * 8;
    __bf16* lA0 = As + (w * 2 + 0) * 512;
    __bf16* lA1 = As + (w * 2 + 1) * 512;
    __bf16* lB0 = Bs + (w * 2 + 0) * 512;
    __bf16* lB1 = Bs + (w * 2 + 1) * 512;

    const __bf16* fa = As + (wm * 64 + l15) * 32 + quad * 8;
    const __bf16* fb = Bs + (wn * 64 + l15) * 32 + quad * 8;

#pragma unroll 1
    for (int kt = 0; kt < DDIM / 32; ++kt) {
        __syncthreads();   // protect LDS from overwrite while prior frags in use
        gload16(gA0, lA0); gload16(gA1, lA1);
        gload16(gB0, lB0); gload16(gB1, lB1);
        gA0 += 32; gA1 += 32; gB0 += 32; gB1 += 32;
        __syncthreads();   // compiler emits vmcnt(0) drain before s_barrier
        bfx8 af[4], bfr[4];
#pragma unroll
        for (int i = 0; i < 4; ++i) {
            af[i]  = *(const bfx8*)(fa + i * 512);
            bfr[i] = *(const bfx8*)(fb + i * 512);
        }
#pragma unroll
        for (int i = 0; i < 4; ++i)
#pragma unroll
            for (int j = 0; j < 4; ++j)
                acc[i][j] = __builtin_amdgcn_mfma_f32_16x16x32_bf16(
                    af[i], bfr[j], acc[i][j], 0, 0, 0);
    }
}

// GEMM1: z = x@Wd + bd ; dbar[row] += mean_cols softplus(z)
__global__ __launch_bounds__(256) void gemm1_kernel(
    const __bf16* __restrict__ xb, const __bf16* __restrict__ WdT,
    const float* __restrict__ bd, float* __restrict__ dbar)
{
    __shared__ __bf16 As[128 * 32];
    __shared__ __bf16 Bs[128 * 32];
    f32x4 acc[4][4];
    f32x4 z4 = {0.f, 0.f, 0.f, 0.f};
#pragma unroll
    for (int i = 0; i < 4; ++i)
#pragma unroll
        for (int j = 0; j < 4; ++j) acc[i][j] = z4;

    const int mbase = blockIdx.y * 128;
    const int nbase = blockIdx.x * 128;
    gemm_core(xb, WdT, As, Bs, mbase, nbase, acc);

    const int lane = threadIdx.x & 63;
    const int w = threadIdx.x >> 6;
    const int quad = lane >> 4;
    const int l15 = lane & 15;
    const int wm = w >> 1, wn = w & 1;
    const float invD = 1.0f / 1024.0f;
#pragma unroll
    for (int i = 0; i < 4; ++i) {
#pragma unroll
        for (int r = 0; r < 4; ++r) {
            float sp = 0.f;
#pragma unroll
            for (int j = 0; j < 4; ++j) {
                int col = nbase + wn * 64 + j * 16 + l15;
                float z = acc[i][j][r] + bd[col];
                sp += fmaxf(z, 0.f) + log1pf(__expf(-fabsf(z)));
            }
#pragma unroll
            for (int off = 1; off < 16; off <<= 1) sp += __shfl_xor(sp, off, 16);
            if (l15 == 0) {
                int row = mbase + wm * 64 + i * 16 + quad * 4 + r;
                atomicAdd(&dbar[row], sp * invD);
            }
        }
    }
}

// GEMM2: out[row][col] = s[row]*(x@Wo)[row][col] + bo[col]
__global__ __launch_bounds__(256) void gemm2_kernel(
    const __bf16* __restrict__ xb, const __bf16* __restrict__ WoT,
    const float* __restrict__ srow, const float* __restrict__ bo,
    float* __restrict__ out)
{
    __shared__ __bf16 As[128 * 32];
    __shared__ __bf16 Bs[128 * 32];
    f32x4 acc[4][4];
    f32x4 z4 = {0.f, 0.f, 0.f, 0.f};
#pragma unroll
    for (int i = 0; i < 4; ++i)
#pragma unroll
        for (int j = 0; j < 4; ++j) acc[i][j] = z4;

    const int mbase = blockIdx.y * 128;
    const int nbase = blockIdx.x * 128;
    gemm_core(xb, WoT, As, Bs, mbase, nbase, acc);

    const int lane = threadIdx.x & 63;
    const int w = threadIdx.x >> 6;
    const int quad = lane >> 4;
    const int l15 = lane & 15;
    const int wm = w >> 1, wn = w & 1;
#pragma unroll
    for (int i = 0; i < 4; ++i) {
        int row0 = mbase + wm * 64 + i * 16 + quad * 4;
#pragma unroll
        for (int r = 0; r < 4; ++r) {
            float sv = srow[row0 + r];
#pragma unroll
            for (int j = 0; j < 4; ++j) {
                int col = nbase + wn * 64 + j * 16 + l15;
                out[(size_t)(row0 + r) * 1024 + col] = sv * acc[i][j][r] + bo[col];
            }
        }
    }
}

// --------------------- chunk-parallel linear scan --------------------------
// h_t = (1-dbar_t) h_{t-1} + dbar_t * Bt_t * sA ;  s_t = <h_t, Ct_t>
// per (b, chunk): local scan from 0, storing s_local, prefix product p.
__global__ __launch_bounds__(256) void scan_kernel(
    const float* __restrict__ dbar, const float* __restrict__ Bt,
    const float* __restrict__ Ct, const float* __restrict__ sA,
    float* __restrict__ s_local, float* __restrict__ pbuf,
    float* __restrict__ Pc, float* __restrict__ Hend)
{
    int tid = threadIdx.x;
    int gid = blockIdx.x * 16 + (tid >> 4);   // 512 groups
    int n = tid & 15;
    int b = gid >> 6;        // / NCHUNK
    int c = gid & 63;        // % NCHUNK
    float sAn = sA[n];
    float h = 0.f, p = 1.f;
    int row = b * TLEN + c * CHUNK;
#pragma unroll 4
    for (int t = 0; t < CHUNK; ++t, ++row) {
        float d = dbar[row];
        float btv = Bt[row * 16 + n];
        float ctv = Ct[row * 16 + n];
        float a = 1.f - d;
        h = h * a + d * sAn * btv;
        p *= a;
        float prod = h * ctv;
#pragma unroll
        for (int off = 1; off < 16; off <<= 1) prod += __shfl_xor(prod, off, 16);
        if (n == 0) { s_local[row] = prod; pbuf[row] = p; }
    }
    Hend[gid * 16 + n] = h;
    if (n == 0) Pc[gid] = p;
}

__global__ __launch_bounds__(128) void stitch_kernel(
    const float* __restrict__ Pc, const float* __restrict__ Hend,
    float* __restrict__ h0buf)
{
    int tid = threadIdx.x;           // 128 = 8 batches x 16 n
    int b = tid >> 4, n = tid & 15;
    float h0 = 0.f;
#pragma unroll 8
    for (int c = 0; c < NCHUNK; ++c) {
        int g = b * NCHUNK + c;
        h0buf[g * 16 + n] = h0;
        h0 = Pc[g] * h0 + Hend[g * 16 + n];
    }
}

__global__ __launch_bounds__(256) void fixup_kernel(
    const float* __restrict__ s_local, const float* __restrict__ pbuf,
    const float* __restrict__ h0buf, const float* __restrict__ Ct,
    float* __restrict__ sbuf)
{
    int row = blockIdx.x * 256 + threadIdx.x;
    int b = row >> 12, t = row & 4095;
    int g = b * NCHUNK + (t >> 6);
    const float4* h4 = (const float4*)(h0buf + g * 16);
    const float4* c4 = (const float4*)(Ct + (size_t)row * 16);
    float dot = 0.f;
#pragma unroll
    for (int q = 0; q < 4; ++q) {
        float4 hv = h4[q], cv = c4[q];
        dot += hv.x * cv.x + hv.y * cv.y + hv.z * cv.z + hv.w * cv.w;
    }
    sbuf[row] = s_local[row] + pbuf[row] * dot;
}

// ---------------------------------------------------------------------------
extern "C" void kernel_launch(void* const* d_in, const int* in_sizes, int n_in,
                              void* d_out, int out_size, void* d_ws, size_t ws_size,
                              hipStream_t stream)
{
    const float* x  = (const float*)d_in[0];
    const float* Wd = (const float*)d_in[1];
    const float* bd = (const float*)d_in[2];
    const float* Wb = (const float*)d_in[3];
    const float* bb = (const float*)d_in[4];
    const float* Wc = (const float*)d_in[5];
    const float* bc = (const float*)d_in[6];
    const float* Wo = (const float*)d_in[7];
    const float* bo = (const float*)d_in[8];
    const float* A  = (const float*)d_in[9];
    float* out = (float*)d_out;

    char* base = (char*)d_ws;
    size_t off = 0;
    auto alloc = [&](size_t bytes) -> void* {
        void* p = base + off;
        off = (off + bytes + 255) & ~(size_t)255;
        return p;
    };
    __bf16* xb   = (__bf16*)alloc((size_t)M_ROWS * DDIM * 2);  // 67 MB
    __bf16* WdT  = (__bf16*)alloc((size_t)DDIM * DDIM * 2);    // 2 MB
    __bf16* WoT  = (__bf16*)alloc((size_t)DDIM * DDIM * 2);    // 2 MB
    __bf16* Wbc  = (__bf16*)alloc(32 * 1024 * 2);              // 64 KB
    float* sAbuf = (float*)alloc(64);
    float* dbar  = (float*)alloc(M_ROWS * 4);
    float* Bt    = (float*)alloc((size_t)M_ROWS * 16 * 4);     // 2 MB
    float* Ct    = (float*)alloc((size_t)M_ROWS * 16 * 4);     // 2 MB
    float* s_loc = (float*)alloc(M_ROWS * 4);
    float* pbuf  = (float*)alloc(M_ROWS * 4);
    float* sbuf  = (float*)alloc(M_ROWS * 4);
    float* Pc    = (float*)alloc(BATCH * NCHUNK * 4);
    float* Hend  = (float*)alloc(BATCH * NCHUNK * 16 * 4);
    float* h0buf = (float*)alloc(BATCH * NCHUNK * 16 * 4);

    transpose_w_kernel<<<2048, 256, 0, stream>>>(Wd, Wo, WdT, WoT);
    wbc_kernel<<<128, 256, 0, stream>>>(Wb, Wc, Wbc);
    sA_kernel<<<1, 256, 0, stream>>>(A, sAbuf);
    cast_kernel<<<M_ROWS * DDIM / 8 / 256, 256, 0, stream>>>(x, xb);
    hipMemsetAsync(dbar, 0, M_ROWS * 4, stream);
    btct_kernel<<<512, 256, 0, stream>>>(xb, Wbc, bb, bc, Bt, Ct);
    gemm1_kernel<<<dim3(8, 256), 256, 0, stream>>>(xb, WdT, bd, dbar);
    scan_kernel<<<32, 256, 0, stream>>>(dbar, Bt, Ct, sAbuf, s_loc, pbuf, Pc, Hend);
    stitch_kernel<<<1, 128, 0, stream>>>(Pc, Hend, h0buf);
    fixup_kernel<<<M_ROWS / 256, 256, 0, stream>>>(s_loc, pbuf, h0buf, Ct, sbuf);
    gemm2_kernel<<<dim3(8, 256), 256, 0, stream>>>(xb, WoT, sbuf, bo, out);
}

// Round 3
// 496.720 us; speedup vs baseline: 2.0277x; 1.2128x over previous
//
#include <hip/hip_runtime.h>
#include <hip/hip_bf16.h>

// ---------------------------------------------------------------------------
// MambaBlock: delta/dbar via bf16 MFMA GEMM1 (fast-softplus+row-mean epilogue),
// Bt/Ct via skinny MFMA GEMM, chunk-parallel linear scan,
// out = diag(s)*(x@Wo)+bo via bf16 MFMA GEMM2 (row-scale epilogue).
// B=8 T=4096 D=1024 N=16, M=B*T=32768.
// ---------------------------------------------------------------------------

typedef __bf16 bfx4 __attribute__((ext_vector_type(4)));
typedef __bf16 bfx8 __attribute__((ext_vector_type(8)));
typedef float  f32x4 __attribute__((ext_vector_type(4)));

#define M_ROWS 32768
#define DDIM   1024
#define NSTATE 16
#define TLEN   4096
#define BATCH  8
#define CHUNK  32
#define NCHUNK 128   // TLEN / CHUNK
#define NGROUP (BATCH * NCHUNK)   // 1024 scan chains

// ---------------- prep: weight transposes + casts --------------------------
// Tiled transpose fp32 -> bf16 for Wd, Wo (1024x1024). 32x32 LDS tiles, +1 pad.
__global__ __launch_bounds__(256) void transpose_w_kernel(
    const float* __restrict__ Wd, const float* __restrict__ Wo,
    __bf16* __restrict__ WdT, __bf16* __restrict__ WoT)
{
    __shared__ float tile[32][33];
    const int bid = blockIdx.x;                 // 0..2047
    const float* src = (bid < 1024) ? Wd : Wo;
    __bf16* dst = (bid < 1024) ? WdT : WoT;
    const int t = bid & 1023;
    const int tr = t >> 5, tc = t & 31;
    const int tx = threadIdx.x & 31, ty = threadIdx.x >> 5;  // ty 0..7
#pragma unroll
    for (int i = 0; i < 4; ++i) {
        int r = ty + i * 8;
        tile[r][tx] = src[(size_t)(tr * 32 + r) * 1024 + tc * 32 + tx];
    }
    __syncthreads();
#pragma unroll
    for (int i = 0; i < 4; ++i) {
        int r = ty + i * 8;
        dst[(size_t)(tc * 32 + r) * 1024 + tr * 32 + tx] = (__bf16)tile[tx][r];
    }
}

// Wbc: [32][1024] bf16 ; rows 0..15 = Wb^T, rows 16..31 = Wc^T
__global__ __launch_bounds__(256) void wbc_kernel(
    const float* __restrict__ Wb, const float* __restrict__ Wc,
    __bf16* __restrict__ Wbc)
{
    int idx = blockIdx.x * 256 + threadIdx.x;   // 0..32767
    int n2 = idx >> 10, k = idx & 1023;
    float v = (n2 < 16) ? Wb[k * 16 + n2] : Wc[k * 16 + (n2 - 16)];
    Wbc[idx] = (__bf16)v;
}

__global__ __launch_bounds__(256) void sA_kernel(const float* __restrict__ A,
                                                 float* __restrict__ sA)
{
    __shared__ float red[256];
    int tid = threadIdx.x;
    int n = tid & 15, part = tid >> 4;
    float sum = 0.f;
    for (int k = part * 64; k < part * 64 + 64; ++k) sum += A[k * 16 + n];
    red[tid] = sum;
    __syncthreads();
    if (tid < 16) {
        float tot = 0.f;
        for (int p = 0; p < 16; ++p) tot += red[p * 16 + tid];
        sA[tid] = 1.f / (1.f + expf(-tot * (1.f / 1024.f)));
    }
}

// ------------------ cast x -> bf16 (pure streaming) ------------------------
__global__ __launch_bounds__(256) void cast_kernel(const float* __restrict__ x,
                                                   __bf16* __restrict__ xb)
{
    size_t i = ((size_t)blockIdx.x * 256 + threadIdx.x) * 8;
    const float4* xg = (const float4*)(x + i);
    float4 v0 = xg[0], v1 = xg[1];
    bfx8 o;
    o[0] = (__bf16)v0.x; o[1] = (__bf16)v0.y; o[2] = (__bf16)v0.z; o[3] = (__bf16)v0.w;
    o[4] = (__bf16)v1.x; o[5] = (__bf16)v1.y; o[6] = (__bf16)v1.z; o[7] = (__bf16)v1.w;
    *(bfx8*)(xb + i) = o;
}

// ---------------- Bt/Ct: skinny MFMA GEMM, no LDS --------------------------
__global__ __launch_bounds__(256) void btct_kernel(
    const __bf16* __restrict__ xb, const __bf16* __restrict__ Wbc,
    const float* __restrict__ bb, const float* __restrict__ bc,
    float* __restrict__ Bt, float* __restrict__ Ct)
{
    const int wid = blockIdx.x * 4 + (threadIdx.x >> 6);  // 0..2047
    const int lane = threadIdx.x & 63;
    const int quad = lane >> 4, l15 = lane & 15;
    const int mbase = wid * 16;
    const __bf16* ga = xb + (size_t)(mbase + l15) * 1024 + quad * 8;
    const __bf16* gb = Wbc + (size_t)l15 * 1024 + quad * 8;
    const __bf16* gc = Wbc + (size_t)(16 + l15) * 1024 + quad * 8;
    f32x4 accB = {0.f, 0.f, 0.f, 0.f};
    f32x4 accC = {0.f, 0.f, 0.f, 0.f};
#pragma unroll 4
    for (int k = 0; k < 1024; k += 32) {
        bfx8 a = *(const bfx8*)ga;  ga += 32;
        bfx8 b = *(const bfx8*)gb;  gb += 32;
        bfx8 c = *(const bfx8*)gc;  gc += 32;
        accB = __builtin_amdgcn_mfma_f32_16x16x32_bf16(a, b, accB, 0, 0, 0);
        accC = __builtin_amdgcn_mfma_f32_16x16x32_bf16(a, c, accC, 0, 0, 0);
    }
    // C/D layout: col = lane&15, row = quad*4 + r
#pragma unroll
    for (int r = 0; r < 4; ++r) {
        int row = mbase + quad * 4 + r;
        Bt[row * 16 + l15] = accB[r] + bb[l15];
        Ct[row * 16 + l15] = accC[r] + bc[l15];
    }
}

// ------------------------- MFMA GEMM core ----------------------------------
__device__ __forceinline__ void gload16(const void* g, void* l)
{
    __builtin_amdgcn_global_load_lds((__attribute__((address_space(1))) void*)g,
                                     (__attribute__((address_space(3))) void*)l,
                                     16, 0, 0);
}

// XCD-aware tile swizzle: blocks resident on one XCD (linear%8) walk a
// contiguous 32-mtile strip, cycling all 8 ntiles before advancing mtile,
// so the 256KB A-strip stays L2-resident per XCD.
__device__ __forceinline__ void tile_swizzle(int L, int& mtile, int& ntile)
{
    int xcd = L & 7;
    int s = L >> 3;           // 0..255
    mtile = xcd * 32 + (s >> 3);
    ntile = s & 7;
}

__device__ __forceinline__ void gemm_core(const __bf16* __restrict__ Abuf,
                                          const __bf16* __restrict__ Bbuf,
                                          __bf16* As, __bf16* Bs,
                                          int mbase, int nbase,
                                          f32x4 acc[4][4])
{
    const int tid = threadIdx.x;
    const int lane = tid & 63;
    const int w = tid >> 6;
    const int quad = lane >> 4;
    const int l15 = lane & 15;
    const int wm = w >> 1, wn = w & 1;

    int lin0 = (w * 2 + 0) * 64 + lane;
    int lin1 = (w * 2 + 1) * 64 + lane;
    const __bf16* gA0 = Abuf + (size_t)(mbase + (lin0 >> 2)) * DDIM + (lin0 & 3) * 8;
    const __bf16* gA1 = Abuf + (size_t)(mbase + (lin1 >> 2)) * DDIM + (lin1 & 3) * 8;
    const __bf16* gB0 = Bbuf + (size_t)(nbase + (lin0 >> 2)) * DDIM + (lin0 & 3) * 8;
    const __bf16* gB1 = Bbuf + (size_t)(nbase + (lin1 >> 2)) * DDIM + (lin1 & 3) * 8;
    __bf16* lA0 = As + (w * 2 + 0) * 512;
    __bf16* lA1 = As + (w * 2 + 1) * 512;
    __bf16* lB0 = Bs + (w * 2 + 0) * 512;
    __bf16* lB1 = Bs + (w * 2 + 1) * 512;

    const __bf16* fa = As + (wm * 64 + l15) * 32 + quad * 8;
    const __bf16* fb = Bs + (wn * 64 + l15) * 32 + quad * 8;

#pragma unroll 1
    for (int kt = 0; kt < DDIM / 32; ++kt) {
        __syncthreads();   // protect LDS from overwrite while prior frags in use
        gload16(gA0, lA0); gload16(gA1, lA1);
        gload16(gB0, lB0); gload16(gB1, lB1);
        gA0 += 32; gA1 += 32; gB0 += 32; gB1 += 32;
        __syncthreads();   // vmcnt(0) drain before s_barrier
        bfx8 af[4], bfr[4];
#pragma unroll
        for (int i = 0; i < 4; ++i) {
            af[i]  = *(const bfx8*)(fa + i * 512);
            bfr[i] = *(const bfx8*)(fb + i * 512);
        }
#pragma unroll
        for (int i = 0; i < 4; ++i)
#pragma unroll
            for (int j = 0; j < 4; ++j)
                acc[i][j] = __builtin_amdgcn_mfma_f32_16x16x32_bf16(
                    af[i], bfr[j], acc[i][j], 0, 0, 0);
    }
}

// GEMM1: z = x@Wd + bd ; dbar[row] += mean_cols softplus(z)
__global__ __launch_bounds__(256) void gemm1_kernel(
    const __bf16* __restrict__ xb, const __bf16* __restrict__ WdT,
    const float* __restrict__ bd, float* __restrict__ dbar)
{
    __shared__ __bf16 As[128 * 32];
    __shared__ __bf16 Bs[128 * 32];
    f32x4 acc[4][4];
    f32x4 z4 = {0.f, 0.f, 0.f, 0.f};
#pragma unroll
    for (int i = 0; i < 4; ++i)
#pragma unroll
        for (int j = 0; j < 4; ++j) acc[i][j] = z4;

    int mtile, ntile;
    tile_swizzle(blockIdx.x, mtile, ntile);
    const int mbase = mtile * 128;
    const int nbase = ntile * 128;
    gemm_core(xb, WdT, As, Bs, mbase, nbase, acc);

    const int lane = threadIdx.x & 63;
    const int w = threadIdx.x >> 6;
    const int quad = lane >> 4;
    const int l15 = lane & 15;
    const int wm = w >> 1, wn = w & 1;
    const float invD = 1.0f / 1024.0f;
#pragma unroll
    for (int i = 0; i < 4; ++i) {
#pragma unroll
        for (int r = 0; r < 4; ++r) {
            float sp = 0.f;
#pragma unroll
            for (int j = 0; j < 4; ++j) {
                int col = nbase + wn * 64 + j * 16 + l15;
                float z = acc[i][j][r] + bd[col];
                // fast softplus: max(z,0) + log(1+exp(-|z|)), HW exp/log
                sp += fmaxf(z, 0.f) + __logf(1.f + __expf(-fabsf(z)));
            }
#pragma unroll
            for (int off = 1; off < 16; off <<= 1) sp += __shfl_xor(sp, off, 16);
            if (l15 == 0) {
                int row = mbase + wm * 64 + i * 16 + quad * 4 + r;
                atomicAdd(&dbar[row], sp * invD);
            }
        }
    }
}

// GEMM2: out[row][col] = s[row]*(x@Wo)[row][col] + bo[col]
__global__ __launch_bounds__(256) void gemm2_kernel(
    const __bf16* __restrict__ xb, const __bf16* __restrict__ WoT,
    const float* __restrict__ srow, const float* __restrict__ bo,
    float* __restrict__ out)
{
    __shared__ __bf16 As[128 * 32];
    __shared__ __bf16 Bs[128 * 32];
    f32x4 acc[4][4];
    f32x4 z4 = {0.f, 0.f, 0.f, 0.f};
#pragma unroll
    for (int i = 0; i < 4; ++i)
#pragma unroll
        for (int j = 0; j < 4; ++j) acc[i][j] = z4;

    int mtile, ntile;
    tile_swizzle(blockIdx.x, mtile, ntile);
    const int mbase = mtile * 128;
    const int nbase = ntile * 128;
    gemm_core(xb, WoT, As, Bs, mbase, nbase, acc);

    const int lane = threadIdx.x & 63;
    const int w = threadIdx.x >> 6;
    const int quad = lane >> 4;
    const int l15 = lane & 15;
    const int wm = w >> 1, wn = w & 1;
#pragma unroll
    for (int i = 0; i < 4; ++i) {
        int row0 = mbase + wm * 64 + i * 16 + quad * 4;
#pragma unroll
        for (int r = 0; r < 4; ++r) {
            float sv = srow[row0 + r];
#pragma unroll
            for (int j = 0; j < 4; ++j) {
                int col = nbase + wn * 64 + j * 16 + l15;
                out[(size_t)(row0 + r) * 1024 + col] = sv * acc[i][j][r] + bo[col];
            }
        }
    }
}

// --------------------- chunk-parallel linear scan --------------------------
// h_t = (1-dbar_t) h_{t-1} + dbar_t * Bt_t * sA ;  s_t = <h_t, Ct_t>
__global__ __launch_bounds__(256) void scan_kernel(
    const float* __restrict__ dbar, const float* __restrict__ Bt,
    const float* __restrict__ Ct, const float* __restrict__ sA,
    float* __restrict__ s_local, float* __restrict__ pbuf,
    float* __restrict__ Pc, float* __restrict__ Hend)
{
    int tid = threadIdx.x;
    int gid = blockIdx.x * 16 + (tid >> 4);   // 0..NGROUP-1
    int n = tid & 15;
    int b = gid >> 7;         // / NCHUNK
    int c = gid & 127;        // % NCHUNK
    float sAn = sA[n];
    float h = 0.f, p = 1.f;
    int row = b * TLEN + c * CHUNK;
#pragma unroll 4
    for (int t = 0; t < CHUNK; ++t, ++row) {
        float d = dbar[row];
        float btv = Bt[row * 16 + n];
        float ctv = Ct[row * 16 + n];
        float a = 1.f - d;
        h = h * a + d * sAn * btv;
        p *= a;
        float prod = h * ctv;
#pragma unroll
        for (int off = 1; off < 16; off <<= 1) prod += __shfl_xor(prod, off, 16);
        if (n == 0) { s_local[row] = prod; pbuf[row] = p; }
    }
    Hend[gid * 16 + n] = h;
    if (n == 0) Pc[gid] = p;
}

__global__ __launch_bounds__(128) void stitch_kernel(
    const float* __restrict__ Pc, const float* __restrict__ Hend,
    float* __restrict__ h0buf)
{
    int tid = threadIdx.x;           // 128 = 8 batches x 16 n
    int b = tid >> 4, n = tid & 15;
    float h0 = 0.f;
#pragma unroll 8
    for (int c = 0; c < NCHUNK; ++c) {
        int g = b * NCHUNK + c;
        h0buf[g * 16 + n] = h0;
        h0 = Pc[g] * h0 + Hend[g * 16 + n];
    }
}

__global__ __launch_bounds__(256) void fixup_kernel(
    const float* __restrict__ s_local, const float* __restrict__ pbuf,
    const float* __restrict__ h0buf, const float* __restrict__ Ct,
    float* __restrict__ sbuf)
{
    int row = blockIdx.x * 256 + threadIdx.x;
    int b = row >> 12, t = row & 4095;
    int g = b * NCHUNK + (t / CHUNK);
    const float4* h4 = (const float4*)(h0buf + g * 16);
    const float4* c4 = (const float4*)(Ct + (size_t)row * 16);
    float dot = 0.f;
#pragma unroll
    for (int q = 0; q < 4; ++q) {
        float4 hv = h4[q], cv = c4[q];
        dot += hv.x * cv.x + hv.y * cv.y + hv.z * cv.z + hv.w * cv.w;
    }
    sbuf[row] = s_local[row] + pbuf[row] * dot;
}

// ---------------------------------------------------------------------------
extern "C" void kernel_launch(void* const* d_in, const int* in_sizes, int n_in,
                              void* d_out, int out_size, void* d_ws, size_t ws_size,
                              hipStream_t stream)
{
    const float* x  = (const float*)d_in[0];
    const float* Wd = (const float*)d_in[1];
    const float* bd = (const float*)d_in[2];
    const float* Wb = (const float*)d_in[3];
    const float* bb = (const float*)d_in[4];
    const float* Wc = (const float*)d_in[5];
    const float* bc = (const float*)d_in[6];
    const float* Wo = (const float*)d_in[7];
    const float* bo = (const float*)d_in[8];
    const float* A  = (const float*)d_in[9];
    float* out = (float*)d_out;

    char* base = (char*)d_ws;
    size_t off = 0;
    auto alloc = [&](size_t bytes) -> void* {
        void* p = base + off;
        off = (off + bytes + 255) & ~(size_t)255;
        return p;
    };
    __bf16* xb   = (__bf16*)alloc((size_t)M_ROWS * DDIM * 2);  // 67 MB
    __bf16* WdT  = (__bf16*)alloc((size_t)DDIM * DDIM * 2);    // 2 MB
    __bf16* WoT  = (__bf16*)alloc((size_t)DDIM * DDIM * 2);    // 2 MB
    __bf16* Wbc  = (__bf16*)alloc(32 * 1024 * 2);              // 64 KB
    float* sAbuf = (float*)alloc(64);
    float* dbar  = (float*)alloc(M_ROWS * 4);
    float* Bt    = (float*)alloc((size_t)M_ROWS * 16 * 4);     // 2 MB
    float* Ct    = (float*)alloc((size_t)M_ROWS * 16 * 4);     // 2 MB
    float* s_loc = (float*)alloc(M_ROWS * 4);
    float* pbuf  = (float*)alloc(M_ROWS * 4);
    float* sbuf  = (float*)alloc(M_ROWS * 4);
    float* Pc    = (float*)alloc(NGROUP * 4);
    float* Hend  = (float*)alloc(NGROUP * 16 * 4);
    float* h0buf = (float*)alloc(NGROUP * 16 * 4);

    transpose_w_kernel<<<2048, 256, 0, stream>>>(Wd, Wo, WdT, WoT);
    wbc_kernel<<<128, 256, 0, stream>>>(Wb, Wc, Wbc);
    sA_kernel<<<1, 256, 0, stream>>>(A, sAbuf);
    cast_kernel<<<M_ROWS * DDIM / 8 / 256, 256, 0, stream>>>(x, xb);
    hipMemsetAsync(dbar, 0, M_ROWS * 4, stream);
    btct_kernel<<<512, 256, 0, stream>>>(xb, Wbc, bb, bc, Bt, Ct);
    gemm1_kernel<<<2048, 256, 0, stream>>>(xb, WdT, bd, dbar);
    scan_kernel<<<NGROUP / 16, 256, 0, stream>>>(dbar, Bt, Ct, sAbuf, s_loc, pbuf, Pc, Hend);
    stitch_kernel<<<1, 128, 0, stream>>>(Pc, Hend, h0buf);
    fixup_kernel<<<M_ROWS / 256, 256, 0, stream>>>(s_loc, pbuf, h0buf, Ct, sbuf);
    gemm2_kernel<<<2048, 256, 0, stream>>>(xb, WoT, sbuf, bo, out);
}